// Round 9
// baseline (168.750 us; speedup 1.0000x reference)
//
#include <hip/hip_runtime.h>
#include <math.h>

// Problem constants
constexpr int B_  = 16;
constexpr int P_  = 1024;
constexpr int Q_  = 512;
constexpr int PD_ = 768;   // p_dim
constexpr int QD_ = 768;   // q_dim
constexpr int CD_ = 1536;  // q_dim + p_dim

#define HUGE_NEG (-1e8f)

typedef __attribute__((ext_vector_type(8))) _Float16 f16x8;
typedef __attribute__((ext_vector_type(4))) _Float16 f16x4;
typedef __attribute__((ext_vector_type(4))) float f32x4;

// async global->LDS DMA, 16B/lane: HW writes lds_base + lane*16 (wave-linear).
__device__ __forceinline__ void dma16(const void* g, void* l) {
  __builtin_amdgcn_global_load_lds((__attribute__((address_space(1))) void*)g,
                                   (__attribute__((address_space(3))) void*)l,
                                   16, 0, 0);
}

// ---------------------------------------------------------------------------
// Deterministic stream compaction: idx[b][0..cnt) = unmasked positions (in
// order), idx[b][cnt..N) = masked positions (in order). nt = max(2, ceil32/32).
// grid = B, block = 256.
// ---------------------------------------------------------------------------
__global__ __launch_bounds__(256) void k_index(const int* __restrict__ mask,
                                               int N, int* __restrict__ idx,
                                               int* __restrict__ cnt,
                                               int* __restrict__ nt) {
  int b = blockIdx.x;
  const int* mb = mask + b * N;
  int* ib = idx + b * N;
  int tid = threadIdx.x;
  int w = tid >> 6, lane = tid & 63;
  int nch = N / 64;
  __shared__ int ccnt[16];
  __shared__ int coff[17];
  for (int c = w; c < nch; c += 4) {
    bool un = (mb[c * 64 + lane] == 0);
    unsigned long long bal = __ballot(un);
    if (lane == 0) ccnt[c] = __popcll(bal);
  }
  __syncthreads();
  if (tid == 0) {
    int s = 0;
    for (int c = 0; c < nch; ++c) {
      coff[c] = s;
      s += ccnt[c];
    }
    coff[nch] = s;
    cnt[b] = s;
    int c32 = (s + 31) & ~31;
    if (c32 < 64) c32 = 64;
    nt[b] = c32 / 32;
  }
  __syncthreads();
  int total = coff[nch];
  for (int c = w; c < nch; c += 4) {
    int e = c * 64 + lane;
    bool un = (mb[e] == 0);
    unsigned long long bal = __ballot(un);
    int pre = __popcll(bal & ((1ull << lane) - 1ull));
    if (un)
      ib[coff[c] + pre] = e;
    else
      ib[total + (c * 64 - coff[c]) + (lane - pre)] = e;
  }
}

// ---------------------------------------------------------------------------
// fp32 -> fp16 convert, 8 elems/thread.
// ---------------------------------------------------------------------------
__global__ __launch_bounds__(256) void k_cvt(const float* __restrict__ src,
                                             _Float16* __restrict__ dst, int n8) {
  int i = blockIdx.x * 256 + threadIdx.x;
  if (i >= n8) return;
  float4 a = ((const float4*)src)[2 * i];
  float4 b = ((const float4*)src)[2 * i + 1];
  f16x8 o = {(_Float16)a.x, (_Float16)a.y, (_Float16)a.z, (_Float16)a.w,
             (_Float16)b.x, (_Float16)b.y, (_Float16)b.z, (_Float16)b.w};
  ((f16x8*)dst)[i] = o;
}

// ---------------------------------------------------------------------------
// Gathered transpose (fp16 src): dstT[b][colOff+c][slot] = src[b][idx[slot]][c]
// 64x64 tiles. grid = (R/64, C/64, B). src L3-resident (just written by k_cvt).
// ---------------------------------------------------------------------------
__global__ __launch_bounds__(256) void k_gprep(const _Float16* __restrict__ src,
                                               const int* __restrict__ idx,
                                               _Float16* __restrict__ dstT,
                                               int R, int C, size_t tBatch,
                                               int colOff) {
  __shared__ _Float16 T[64][72];
  __shared__ int sIdx[64];
  int r0 = blockIdx.x * 64, c0 = blockIdx.y * 64, b = blockIdx.z;
  int tid = threadIdx.x;
  if (tid < 64) sIdx[tid] = idx[b * R + r0 + tid];
  __syncthreads();
  const _Float16* S = src + (size_t)b * R * C;
  int rr = tid >> 4;
  int cc = (tid & 15) * 4;
#pragma unroll
  for (int k = 0; k < 4; ++k) {
    int r = rr + k * 16;
    f16x4 h = *(const f16x4*)(S + (size_t)sIdx[r] * C + c0 + cc);
    T[cc + 0][r] = h[0];
    T[cc + 1][r] = h[1];
    T[cc + 2][r] = h[2];
    T[cc + 3][r] = h[3];
  }
  __syncthreads();
  int cr = tid >> 2;
  int rc = (tid & 3) * 16;
  _Float16* D = dstT + (size_t)b * tBatch + (size_t)(colOff + c0 + cr) * R + r0;
  *(f16x8*)(D + rc) = *(f16x8*)&T[cr][rc];
  *(f16x8*)(D + rc + 8) = *(f16x8*)&T[cr][rc + 8];
}

// ---------------------------------------------------------------------------
// Fused weights: block covers 64 p-slots x 64 q-slots. Merges stat partials,
// one gathered aff read ->
//   WP[b][origP][q_slot]  (zero at q_slot >= cntQ; exact fp32 underflow)
//   WQ[b][q_slot][p_slot] (zero at p_slot >= cntP)
// grid = (P/64, Q/64, B)
// ---------------------------------------------------------------------------
__global__ __launch_bounds__(256) void k_w(
    const float* __restrict__ aff, const int* __restrict__ idxP_,
    const int* __restrict__ cntP_, const int* __restrict__ cntQ_,
    const float* __restrict__ rpm, const float* __restrict__ rps,
    const float* __restrict__ pmax_part, const float* __restrict__ psum_part,
    _Float16* __restrict__ WP, _Float16* __restrict__ WQ) {
  __shared__ _Float16 T[64][72];
  __shared__ float rmx[64], rin[64], cmx[64], cin[64];
  __shared__ int sIdx[64];
  int s0 = blockIdx.x * 64, q0 = blockIdx.y * 64, b = blockIdx.z;
  int tid = threadIdx.x;
  int cntP = cntP_[b], cntQ = cntQ_[b];
  if (tid < 64) {
    int op = idxP_[b * P_ + s0 + tid];
    sIdx[tid] = op;
    float m = -INFINITY;
#pragma unroll
    for (int z = 0; z < 4; ++z) m = fmaxf(m, rpm[(b * 4 + z) * P_ + op]);
    float s = 0.f;
#pragma unroll
    for (int z = 0; z < 4; ++z)
      s += rps[(b * 4 + z) * P_ + op] * __expf(rpm[(b * 4 + z) * P_ + op] - m);
    rmx[tid] = m;
    rin[tid] = 1.0f / s;
  } else if (tid < 128) {
    int t = tid - 64;
    int qq = q0 + t;  // slot
    float m = -INFINITY;
#pragma unroll
    for (int z = 0; z < 4; ++z) m = fmaxf(m, pmax_part[(b * 4 + z) * Q_ + qq]);
    float s = 0.f;
#pragma unroll
    for (int z = 0; z < 4; ++z)
      s += psum_part[(b * 4 + z) * Q_ + qq] *
           __expf(pmax_part[(b * 4 + z) * Q_ + qq] - m);
    cmx[t] = m;
    cin[t] = 1.0f / s;
  }
  __syncthreads();
  const float* A = aff + (size_t)b * P_ * Q_;
  int rr = tid >> 4;
  int cc = (tid & 15) * 4;
  int qm[4];
#pragma unroll
  for (int j = 0; j < 4; ++j) qm[j] = (q0 + cc + j >= cntQ);
#pragma unroll
  for (int k = 0; k < 4; ++k) {
    int r = rr + k * 16;
    int orig = sIdx[r];
    int msk = (s0 + r >= cntP);
    float4 v = *(const float4*)(A + (size_t)orig * Q_ + q0 + cc);
    float vv[4] = {v.x, v.y, v.z, v.w};
    f16x4 wp;
#pragma unroll
    for (int j = 0; j < 4; ++j) {
      wp[j] = (_Float16)(__expf((qm[j] ? HUGE_NEG : vv[j]) - rmx[r]) * rin[r]);
      T[cc + j][r] =
          (_Float16)(__expf((msk ? HUGE_NEG : vv[j]) - cmx[cc + j]) * cin[cc + j]);
    }
    *(f16x4*)(WP + ((size_t)b * P_ + orig) * Q_ + q0 + cc) = wp;
  }
  __syncthreads();
  int cr = tid >> 2;
  int rc = (tid & 3) * 16;
  _Float16* D = WQ + ((size_t)b * Q_ + q0 + cr) * P_ + s0;
  *(f16x8*)(D + rc) = *(f16x8*)&T[cr][rc];
  *(f16x8*)(D + rc + 8) = *(f16x8*)&T[cr][rc + 8];
}

// ---------------------------------------------------------------------------
// GEMM core 8-wave (r8-proven pipeline): 256x128 tile, 8 waves (4Mx2N),
// BK=32, 3-buffer 2-deep prefetch, counted vmcnt (6/3/0), raw barriers,
// chunk-XOR LDS swizzle, 16x16x32 MFMA. Per-lane global bases precomputed by
// caller (enables free row-gather); runtime NT (>= 2).
// ---------------------------------------------------------------------------
__device__ __forceinline__ void gemm_core(const _Float16* pA0,
                                          const _Float16* pA1,
                                          const _Float16* pB0, _Float16* As,
                                          _Float16* Bs, f32x4 (&acc)[4][4],
                                          int w, int l, int NT) {
  constexpr int ASZ = 256 * 32, BSZ = 128 * 32;
  int fr = l & 15;
  int fsw = (((l >> 4) ^ ((fr >> 1) & 3))) * 8;
  int wr = w >> 1, wc = w & 1;

  auto stage = [&](int buf, int t) {
    _Float16* la = As + buf * ASZ + (w * 32) * 32;
    _Float16* lb = Bs + buf * BSZ + (w * 16) * 32;
    dma16(pA0 + t * 32, la);
    dma16(pA1 + t * 32, la + 16 * 32);
    dma16(pB0 + t * 32, lb);
  };
  auto compute = [&](int buf) {
    const _Float16* A0 = As + buf * ASZ;
    const _Float16* B0 = Bs + buf * BSZ;
    f16x8 a[4];
#pragma unroll
    for (int m = 0; m < 4; ++m)
      a[m] = *(const f16x8*)(A0 + (wr * 64 + m * 16 + fr) * 32 + fsw);
#pragma unroll
    for (int n = 0; n < 4; ++n) {
      f16x8 bn = *(const f16x8*)(B0 + (wc * 64 + n * 16 + fr) * 32 + fsw);
#pragma unroll
      for (int m = 0; m < 4; ++m)
        acc[m][n] =
            __builtin_amdgcn_mfma_f32_16x16x32_f16(a[m], bn, acc[m][n], 0, 0, 0);
    }
  };

  stage(0, 0);
  stage(1, 1);
  int b0 = 0, b1 = 1, b2 = 2;
#pragma unroll 3
  for (int t = 0; t < NT - 2; ++t) {
    stage(b2, t + 2);
    asm volatile("s_waitcnt vmcnt(6)" ::: "memory");
    __builtin_amdgcn_s_barrier();
    __builtin_amdgcn_sched_barrier(0);
    compute(b0);
    __builtin_amdgcn_s_barrier();
    int tmp = b0; b0 = b1; b1 = b2; b2 = tmp;
  }
  asm volatile("s_waitcnt vmcnt(3)" ::: "memory");
  __builtin_amdgcn_s_barrier();
  __builtin_amdgcn_sched_barrier(0);
  compute(b0);
  __builtin_amdgcn_s_barrier();
  asm volatile("s_waitcnt vmcnt(0)" ::: "memory");
  __builtin_amdgcn_s_barrier();
  __builtin_amdgcn_sched_barrier(0);
  compute(b1);
}

#define LANE_BASES()                          \
  int rA = w * 32 + (l >> 2);                 \
  int rB = w * 16 + (l >> 2);                 \
  int sk = ((l & 3) ^ ((l >> 3) & 3)) * 8;

// bijective XCD swizzle (nwg % 8 == 0); N-tile 128, M-tile 256
#define SWZ_DECODE(GX, GY)                                          \
  int lin = blockIdx.x + (GX) * (blockIdx.y + (GY) * blockIdx.z);   \
  constexpr int NWG = (GX) * (GY) * B_;                             \
  int w8 = (lin & 7) * (NWG / 8) + (lin >> 3);                      \
  int j0 = (w8 % (GX)) * 128;                                       \
  int t_ = w8 / (GX);                                               \
  int i0 = (t_ % (GY)) * 256;                                       \
  int b = t_ / (GY);

// ---------------------------------------------------------------------------
// K1: qp[b][slot][pd] = sum_d q16[idxQ[slot]][d] * W16[pd][d]  (A row-gather)
// grid (PD/128, Q/256, B)
// ---------------------------------------------------------------------------
__global__ __launch_bounds__(512, 4) void k1_proj(
    const _Float16* __restrict__ q16, const _Float16* __restrict__ W16,
    const int* __restrict__ idxQ, _Float16* __restrict__ qp) {
  __shared__ alignas(16) _Float16 As[3 * 256 * 32];
  __shared__ alignas(16) _Float16 Bs[3 * 128 * 32];
  SWZ_DECODE(PD_ / 128, Q_ / 256)
  int tid = threadIdx.x, w = tid >> 6, l = tid & 63;
  LANE_BASES()
  const _Float16* qb = q16 + (size_t)b * Q_ * QD_;
  int o0 = idxQ[b * Q_ + i0 + rA];
  int o1 = idxQ[b * Q_ + i0 + rA + 16];
  f32x4 acc[4][4];
#pragma unroll
  for (int m = 0; m < 4; ++m)
#pragma unroll
    for (int n = 0; n < 4; ++n) acc[m][n] = (f32x4){0.f, 0.f, 0.f, 0.f};
  gemm_core(qb + (size_t)o0 * QD_ + sk, qb + (size_t)o1 * QD_ + sk,
            W16 + (size_t)(j0 + rB) * QD_ + sk, As, Bs, acc, w, l, QD_ / 32);
  int wr = w >> 1, wc = w & 1, fr = l & 15, fq = l >> 4;
  _Float16* O = qp + (size_t)b * Q_ * PD_;
#pragma unroll
  for (int m = 0; m < 4; ++m) {
    int rl = wr * 64 + m * 16 + fq * 4;
#pragma unroll
    for (int n = 0; n < 4; ++n) {
      int cl = wc * 64 + n * 16 + fr;
#pragma unroll
      for (int r = 0; r < 4; ++r)
        O[(size_t)(i0 + rl + r) * PD_ + j0 + cl] = (_Float16)acc[m][n][r];
    }
  }
}

// ---------------------------------------------------------------------------
// K2: aff[b][p][slot] = sum_d p16[p][d] * qp[slot][d]. grid (Q/128, P/256, B)
// Epilogue: fp32 aff write + softmax-stat partials:
//   col partials per q-slot (over 256 p-rows, pmask) -> pmax/psum[z=i0/256]
//   row partials per orig p (over 128 q-slots, slot>=cntQ masked) -> rpm/rps
// ---------------------------------------------------------------------------
__global__ __launch_bounds__(512, 4) void k2_aff(
    const _Float16* __restrict__ p16, const _Float16* __restrict__ qp,
    const int* __restrict__ pmask, const int* __restrict__ cntQ_,
    float* __restrict__ aff, float* __restrict__ pmax_part,
    float* __restrict__ psum_part, float* __restrict__ rpm,
    float* __restrict__ rps) {
  __shared__ alignas(16) _Float16 As[3 * 256 * 32];
  __shared__ alignas(16) _Float16 Bs[3 * 128 * 32];
  SWZ_DECODE(Q_ / 128, P_ / 256)
  int tid = threadIdx.x, w = tid >> 6, l = tid & 63;
  LANE_BASES()
  const _Float16* pb = p16 + (size_t)b * P_ * PD_;
  const _Float16* qpb = qp + (size_t)b * Q_ * PD_;
  f32x4 acc[4][4];
#pragma unroll
  for (int m = 0; m < 4; ++m)
#pragma unroll
    for (int n = 0; n < 4; ++n) acc[m][n] = (f32x4){0.f, 0.f, 0.f, 0.f};
  gemm_core(pb + (size_t)(i0 + rA) * PD_ + sk,
            pb + (size_t)(i0 + rA + 16) * PD_ + sk,
            qpb + (size_t)(j0 + rB) * PD_ + sk, As, Bs, acc, w, l, PD_ / 32);
  int wr = w >> 1, wc = w & 1, fr = l & 15, fq = l >> 4;
  float* Cb = aff + (size_t)b * P_ * Q_;
#pragma unroll
  for (int m = 0; m < 4; ++m) {
    int rl = wr * 64 + m * 16 + fq * 4;
#pragma unroll
    for (int n = 0; n < 4; ++n) {
      int cl = wc * 64 + n * 16 + fr;
#pragma unroll
      for (int r = 0; r < 4; ++r)
        Cb[(size_t)(i0 + rl + r) * Q_ + j0 + cl] = acc[m][n][r];
    }
  }
  // ---- fused softmax stat partials ----
  const int* pmb = pmask + b * P_ + i0;
  unsigned pmbits = 0;
#pragma unroll
  for (int m = 0; m < 4; ++m)
#pragma unroll
    for (int r = 0; r < 4; ++r)
      pmbits |= (pmb[wr * 64 + m * 16 + fq * 4 + r] ? 1u : 0u) << (m * 4 + r);
  int cQ = cntQ_[b];
  int qmv[4];
  {
    int cbase = j0 + wc * 64 + fr;
#pragma unroll
    for (int n = 0; n < 4; ++n) qmv[n] = (cbase + n * 16) >= cQ;
  }
  __syncthreads();
  float* scr = (float*)As;
  float* cm_ = scr;         // [4][128]
  float* cs_ = scr + 512;
  float* rm_ = scr + 1024;  // [2][256]
  float* rs_ = scr + 1536;

#pragma unroll
  for (int n = 0; n < 4; ++n) {
    float ml = -1e30f;
#pragma unroll
    for (int m = 0; m < 4; ++m)
#pragma unroll
      for (int r = 0; r < 4; ++r) {
        float v = ((pmbits >> (m * 4 + r)) & 1) ? HUGE_NEG : acc[m][n][r];
        ml = fmaxf(ml, v);
      }
    float sl = 0.f;
#pragma unroll
    for (int m = 0; m < 4; ++m)
#pragma unroll
      for (int r = 0; r < 4; ++r) {
        float v = ((pmbits >> (m * 4 + r)) & 1) ? HUGE_NEG : acc[m][n][r];
        sl += __expf(v - ml);
      }
#pragma unroll
    for (int off = 16; off <= 32; off <<= 1) {
      float om = __shfl_xor(ml, off);
      float os = __shfl_xor(sl, off);
      float nm = fmaxf(ml, om);
      sl = sl * __expf(ml - nm) + os * __expf(om - nm);
      ml = nm;
    }
    if (fq == 0) {
      int col = wc * 64 + n * 16 + fr;
      cm_[wr * 128 + col] = ml;
      cs_[wr * 128 + col] = sl;
    }
  }
#pragma unroll
  for (int m = 0; m < 4; ++m)
#pragma unroll
    for (int r = 0; r < 4; ++r) {
      float ml = -1e30f;
#pragma unroll
      for (int n = 0; n < 4; ++n) {
        float v = qmv[n] ? HUGE_NEG : acc[m][n][r];
        ml = fmaxf(ml, v);
      }
      float sl = 0.f;
#pragma unroll
      for (int n = 0; n < 4; ++n) {
        float v = qmv[n] ? HUGE_NEG : acc[m][n][r];
        sl += __expf(v - ml);
      }
#pragma unroll
      for (int off = 1; off <= 8; off <<= 1) {
        float om = __shfl_xor(ml, off);
        float os = __shfl_xor(sl, off);
        float nm = fmaxf(ml, om);
        sl = sl * __expf(ml - nm) + os * __expf(om - nm);
        ml = nm;
      }
      if (fr == 0) {
        int row = wr * 64 + m * 16 + fq * 4 + r;
        rm_[wc * 256 + row] = ml;
        rs_[wc * 256 + row] = sl;
      }
    }
  __syncthreads();
  if (tid < 128) {
    float nm = fmaxf(fmaxf(cm_[tid], cm_[128 + tid]),
                     fmaxf(cm_[256 + tid], cm_[384 + tid]));
    float ns = cs_[tid] * __expf(cm_[tid] - nm) +
               cs_[128 + tid] * __expf(cm_[128 + tid] - nm) +
               cs_[256 + tid] * __expf(cm_[256 + tid] - nm) +
               cs_[384 + tid] * __expf(cm_[384 + tid] - nm);
    int z = i0 >> 8;
    pmax_part[(b * 4 + z) * Q_ + j0 + tid] = nm;
    psum_part[(b * 4 + z) * Q_ + j0 + tid] = ns;
  } else if (tid >= 256) {
    int t = tid - 256;
    float m0 = rm_[t], m1 = rm_[256 + t];
    float s0 = rs_[t], s1 = rs_[256 + t];
    float nm = fmaxf(m0, m1);
    float ns = s0 * __expf(m0 - nm) + s1 * __expf(m1 - nm);
    int zj = j0 >> 7;
    rpm[(b * 4 + zj) * P_ + i0 + t] = nm;
    rps[(b * 4 + zj) * P_ + i0 + t] = ns;
  }
}

// ---------------------------------------------------------------------------
// K4: out2[b][idxQ[slot]][d] = sum_{p-slots<NT*32} WQ[slot][ps] * pTc[d][ps]
// Also writes candT[b][768+d][slot]. Runtime NT = ntP[b] (~halved K).
// grid (PD/128, Q/256, B)
// ---------------------------------------------------------------------------
__global__ __launch_bounds__(512, 4) void k4_attn(
    const _Float16* __restrict__ WQ, const _Float16* __restrict__ pTc,
    const int* __restrict__ idxQ, const int* __restrict__ ntP_,
    float* __restrict__ out2, _Float16* __restrict__ candT) {
  __shared__ alignas(16) _Float16 As[3 * 256 * 32];
  __shared__ alignas(16) _Float16 Bs[3 * 128 * 32];
  SWZ_DECODE(PD_ / 128, Q_ / 256)
  int tid = threadIdx.x, w = tid >> 6, l = tid & 63;
  LANE_BASES()
  const _Float16* Ab = WQ + (size_t)b * Q_ * P_;
  const _Float16* Bb = pTc + (size_t)b * PD_ * P_;
  int NT = ntP_[b];
  f32x4 acc[4][4];
#pragma unroll
  for (int m = 0; m < 4; ++m)
#pragma unroll
    for (int n = 0; n < 4; ++n) acc[m][n] = (f32x4){0.f, 0.f, 0.f, 0.f};
  gemm_core(Ab + (size_t)(i0 + rA) * P_ + sk,
            Ab + (size_t)(i0 + rA + 16) * P_ + sk,
            Bb + (size_t)(j0 + rB) * P_ + sk, As, Bs, acc, w, l, NT);
  int wr = w >> 1, wc = w & 1, fr = l & 15, fq = l >> 4;
  float* Cb = out2 + (size_t)b * Q_ * PD_;
  _Float16* Tb = candT + (size_t)b * CD_ * Q_;
  const int* iq = idxQ + b * Q_;
#pragma unroll
  for (int m = 0; m < 4; ++m) {
    int rl = wr * 64 + m * 16 + fq * 4;
    int oq[4];
#pragma unroll
    for (int r = 0; r < 4; ++r) oq[r] = iq[i0 + rl + r];
#pragma unroll
    for (int n = 0; n < 4; ++n) {
      int cl = wc * 64 + n * 16 + fr;
      f16x4 cv;
#pragma unroll
      for (int r = 0; r < 4; ++r) {
        float v = acc[m][n][r];
        Cb[(size_t)oq[r] * PD_ + j0 + cl] = v;
        cv[r] = (_Float16)v;
      }
      *(f16x4*)(Tb + (size_t)(QD_ + j0 + cl) * Q_ + i0 + rl) = cv;
    }
  }
}

// ---------------------------------------------------------------------------
// K5: out1[b][p][c] = sum_{q-slots<NT*32} WP[p][qs] * candT[c][qs]
// Runtime NT = ntQ[b] (~halved K). grid (CD/128, P/256, B)
// ---------------------------------------------------------------------------
__global__ __launch_bounds__(512, 4) void k5_attn(
    const _Float16* __restrict__ WP, const _Float16* __restrict__ candT,
    const int* __restrict__ ntQ_, float* __restrict__ out1) {
  __shared__ alignas(16) _Float16 As[3 * 256 * 32];
  __shared__ alignas(16) _Float16 Bs[3 * 128 * 32];
  SWZ_DECODE(CD_ / 128, P_ / 256)
  int tid = threadIdx.x, w = tid >> 6, l = tid & 63;
  LANE_BASES()
  const _Float16* Ab = WP + (size_t)b * P_ * Q_;
  const _Float16* Bb = candT + (size_t)b * CD_ * Q_;
  int NT = ntQ_[b];
  f32x4 acc[4][4];
#pragma unroll
  for (int m = 0; m < 4; ++m)
#pragma unroll
    for (int n = 0; n < 4; ++n) acc[m][n] = (f32x4){0.f, 0.f, 0.f, 0.f};
  gemm_core(Ab + (size_t)(i0 + rA) * Q_ + sk,
            Ab + (size_t)(i0 + rA + 16) * Q_ + sk,
            Bb + (size_t)(j0 + rB) * Q_ + sk, As, Bs, acc, w, l, NT);
  int wr = w >> 1, wc = w & 1, fr = l & 15, fq = l >> 4;
  float* Cb = out1 + (size_t)b * P_ * CD_;
#pragma unroll
  for (int m = 0; m < 4; ++m) {
    int rl = wr * 64 + m * 16 + fq * 4;
#pragma unroll
    for (int n = 0; n < 4; ++n) {
      int cl = wc * 64 + n * 16 + fr;
#pragma unroll
      for (int r = 0; r < 4; ++r)
        Cb[(size_t)(i0 + rl + r) * CD_ + j0 + cl] = acc[m][n][r];
    }
  }
}

// ---------------------------------------------------------------------------
extern "C" void kernel_launch(void* const* d_in, const int* in_sizes, int n_in,
                              void* d_out, int out_size, void* d_ws,
                              size_t ws_size, hipStream_t stream) {
  const float* p = (const float*)d_in[0];
  const float* q = (const float*)d_in[1];
  const int* pmask = (const int*)d_in[2];
  const int* qmask = (const int*)d_in[3];
  const float* W = (const float*)d_in[4];
  float* out = (float*)d_out;

  char* ws = (char*)d_ws;
  size_t off = 0;
  auto alloc = [&](size_t bytes) {
    void* r = ws + off;
    off += (bytes + 255) & ~(size_t)255;
    return r;
  };
  _Float16* q16 = (_Float16*)alloc((size_t)B_ * Q_ * QD_ * 2);
  _Float16* p16 = (_Float16*)alloc((size_t)B_ * P_ * PD_ * 2);
  _Float16* pTc = (_Float16*)alloc((size_t)B_ * PD_ * P_ * 2);
  _Float16* candT = (_Float16*)alloc((size_t)B_ * CD_ * Q_ * 2);
  _Float16* W16 = (_Float16*)alloc((size_t)PD_ * QD_ * 2);
  _Float16* qp16 = (_Float16*)alloc((size_t)B_ * Q_ * PD_ * 2);
  float* aff = (float*)alloc((size_t)B_ * P_ * Q_ * 4);
  _Float16* WP = (_Float16*)alloc((size_t)B_ * P_ * Q_ * 2);
  _Float16* WQ = (_Float16*)alloc((size_t)B_ * Q_ * P_ * 2);
  float* pmax_part = (float*)alloc((size_t)B_ * 4 * Q_ * 4);
  float* psum_part = (float*)alloc((size_t)B_ * 4 * Q_ * 4);
  float* rpm = (float*)alloc((size_t)B_ * 4 * P_ * 4);
  float* rps = (float*)alloc((size_t)B_ * 4 * P_ * 4);
  int* idxP = (int*)alloc((size_t)B_ * P_ * 4);
  int* idxQ = (int*)alloc((size_t)B_ * Q_ * 4);
  int* cntP = (int*)alloc(B_ * 4);
  int* cntQ = (int*)alloc(B_ * 4);
  int* ntP = (int*)alloc(B_ * 4);
  int* ntQ = (int*)alloc(B_ * 4);

  float* out1 = out;                          // [B,P,1536]
  float* out2 = out + (size_t)B_ * P_ * CD_;  // [B,Q,768]

  // 1. mask compaction (deterministic)
  k_index<<<B_, 256, 0, stream>>>(pmask, P_, idxP, cntP, ntP);
  k_index<<<B_, 256, 0, stream>>>(qmask, Q_, idxQ, cntQ, ntQ);
  // 2. fp16 conversions (row-major, original order)
  k_cvt<<<PD_ * QD_ / 8 / 256, 256, 0, stream>>>(W, W16, PD_ * QD_ / 8);
  k_cvt<<<B_ * Q_ * QD_ / 8 / 256, 256, 0, stream>>>(q, q16, B_ * Q_ * QD_ / 8);
  k_cvt<<<B_ * P_ * PD_ / 8 / 256, 256, 0, stream>>>(p, p16, B_ * P_ * PD_ / 8);
  // 3. gathered transposes (L3-hot sources)
  k_gprep<<<dim3(Q_ / 64, QD_ / 64, B_), 256, 0, stream>>>(
      q16, idxQ, candT, Q_, QD_, (size_t)CD_ * Q_, 0);  // candT cols 0..767
  k_gprep<<<dim3(P_ / 64, PD_ / 64, B_), 256, 0, stream>>>(
      p16, idxP, pTc, P_, PD_, (size_t)PD_ * P_, 0);
  // 4. K1 projection (A rows gathered by idxQ -> qp in slot order)
  k1_proj<<<dim3(PD_ / 128, Q_ / 256, B_), 512, 0, stream>>>(q16, W16, idxQ,
                                                             qp16);
  // 5. K2 affinity (cols = q-slots) + fused stat partials
  k2_aff<<<dim3(Q_ / 128, P_ / 256, B_), 512, 0, stream>>>(
      p16, qp16, pmask, cntQ, aff, pmax_part, psum_part, rpm, rps);
  // 6. fused weights (gathered p rows; compacted WP/WQ)
  k_w<<<dim3(P_ / 64, Q_ / 64, B_), 256, 0, stream>>>(
      aff, idxP, cntP, cntQ, rpm, rps, pmax_part, psum_part, WP, WQ);
  // 7. K4 -> out2 (rows ungathered via idxQ) + candT upper half; K ~ cntP
  k4_attn<<<dim3(PD_ / 128, Q_ / 256, B_), 512, 0, stream>>>(WQ, pTc, idxQ,
                                                             ntP, out2, candT);
  // 8. K5 -> out1; K ~ cntQ
  k5_attn<<<dim3(CD_ / 128, P_ / 256, B_), 512, 0, stream>>>(WP, candT, ntQ,
                                                             out1);
}

// Round 10
// 162.080 us; speedup vs baseline: 1.0412x; 1.0412x over previous
//
#include <hip/hip_runtime.h>
#include <math.h>

// Problem constants
constexpr int B_  = 16;
constexpr int P_  = 1024;
constexpr int Q_  = 512;
constexpr int PD_ = 768;   // p_dim
constexpr int QD_ = 768;   // q_dim
constexpr int CD_ = 1536;  // q_dim + p_dim

#define HUGE_NEG (-1e8f)

typedef __attribute__((ext_vector_type(8))) _Float16 f16x8;
typedef __attribute__((ext_vector_type(4))) _Float16 f16x4;
typedef __attribute__((ext_vector_type(4))) float f32x4;

// async global->LDS DMA, 16B/lane: HW writes lds_base + lane*16 (wave-linear).
__device__ __forceinline__ void dma16(const void* g, void* l) {
  __builtin_amdgcn_global_load_lds((__attribute__((address_space(1))) void*)g,
                                   (__attribute__((address_space(3))) void*)l,
                                   16, 0, 0);
}

// ---------------------------------------------------------------------------
// Deterministic stream compaction: idx[b][0..cnt) = unmasked positions (in
// order), idx[b][cnt..N) = masked positions (in order). nt = max(2, ceil32/32).
// grid = B, block = 256.
// ---------------------------------------------------------------------------
__global__ __launch_bounds__(256) void k_index(const int* __restrict__ mask,
                                               int N, int* __restrict__ idx,
                                               int* __restrict__ cnt,
                                               int* __restrict__ nt) {
  int b = blockIdx.x;
  const int* mb = mask + b * N;
  int* ib = idx + b * N;
  int tid = threadIdx.x;
  int w = tid >> 6, lane = tid & 63;
  int nch = N / 64;
  __shared__ int ccnt[16];
  __shared__ int coff[17];
  for (int c = w; c < nch; c += 4) {
    bool un = (mb[c * 64 + lane] == 0);
    unsigned long long bal = __ballot(un);
    if (lane == 0) ccnt[c] = __popcll(bal);
  }
  __syncthreads();
  if (tid == 0) {
    int s = 0;
    for (int c = 0; c < nch; ++c) {
      coff[c] = s;
      s += ccnt[c];
    }
    coff[nch] = s;
    cnt[b] = s;
    int c32 = (s + 31) & ~31;
    if (c32 < 64) c32 = 64;
    nt[b] = c32 / 32;
  }
  __syncthreads();
  int total = coff[nch];
  for (int c = w; c < nch; c += 4) {
    int e = c * 64 + lane;
    bool un = (mb[e] == 0);
    unsigned long long bal = __ballot(un);
    int pre = __popcll(bal & ((1ull << lane) - 1ull));
    if (un)
      ib[coff[c] + pre] = e;
    else
      ib[total + (c * 64 - coff[c]) + (lane - pre)] = e;
  }
}

// ---------------------------------------------------------------------------
// fp32 -> fp16 convert, 8 elems/thread (W only).
// ---------------------------------------------------------------------------
__global__ __launch_bounds__(256) void k_cvt(const float* __restrict__ src,
                                             _Float16* __restrict__ dst, int n8) {
  int i = blockIdx.x * 256 + threadIdx.x;
  if (i >= n8) return;
  float4 a = ((const float4*)src)[2 * i];
  float4 b = ((const float4*)src)[2 * i + 1];
  f16x8 o = {(_Float16)a.x, (_Float16)a.y, (_Float16)a.z, (_Float16)a.w,
             (_Float16)b.x, (_Float16)b.y, (_Float16)b.z, (_Float16)b.w};
  ((f16x8*)dst)[i] = o;
}

// ---------------------------------------------------------------------------
// Fused prep with gather: ONE fp32 read of src[b][idx[slot]][c] tile ->
//   dst16[b][orig][c]   fp16 row-major, ORIGINAL row order (scatter rows)
//   dstT[b][colOff+c][slot] fp16 transposed, SLOT order
// 64x64 tiles. grid = (R/64, C/64, B)
// ---------------------------------------------------------------------------
__global__ __launch_bounds__(256) void k_prep_g(const float* __restrict__ src,
                                                const int* __restrict__ idx,
                                                _Float16* __restrict__ dst16,
                                                _Float16* __restrict__ dstT,
                                                int R, int C, size_t tBatch,
                                                int colOff) {
  __shared__ _Float16 T[64][72];
  __shared__ int sIdx[64];
  int r0 = blockIdx.x * 64, c0 = blockIdx.y * 64, b = blockIdx.z;
  int tid = threadIdx.x;
  if (tid < 64) sIdx[tid] = idx[b * R + r0 + tid];
  __syncthreads();
  const float* S = src + (size_t)b * R * C;
  _Float16* D16 = dst16 + (size_t)b * R * C;
  int rr = tid >> 4;
  int cc = (tid & 15) * 4;
#pragma unroll
  for (int k = 0; k < 4; ++k) {
    int r = rr + k * 16;
    int orig = sIdx[r];
    float4 v = *(const float4*)(S + (size_t)orig * C + c0 + cc);
    f16x4 h = {(_Float16)v.x, (_Float16)v.y, (_Float16)v.z, (_Float16)v.w};
    *(f16x4*)(D16 + (size_t)orig * C + c0 + cc) = h;
    T[cc + 0][r] = h[0];
    T[cc + 1][r] = h[1];
    T[cc + 2][r] = h[2];
    T[cc + 3][r] = h[3];
  }
  __syncthreads();
  int cr = tid >> 2;
  int rc = (tid & 3) * 16;
  _Float16* D = dstT + (size_t)b * tBatch + (size_t)(colOff + c0 + cr) * R + r0;
  *(f16x8*)(D + rc) = *(f16x8*)&T[cr][rc];
  *(f16x8*)(D + rc + 8) = *(f16x8*)&T[cr][rc + 8];
}

// ---------------------------------------------------------------------------
// Fused weights: block covers 64 p-slots x 64 q-slots. Merges stat partials,
// one gathered aff read ->
//   WP[b][origP][q_slot]  (zero at q_slot >= cntQ; exact fp32 underflow)
//   WQ[b][q_slot][p_slot] (zero at p_slot >= cntP)
// grid = (P/64, Q/64, B)
// ---------------------------------------------------------------------------
__global__ __launch_bounds__(256) void k_w(
    const float* __restrict__ aff, const int* __restrict__ idxP_,
    const int* __restrict__ cntP_, const int* __restrict__ cntQ_,
    const float* __restrict__ rpm, const float* __restrict__ rps,
    const float* __restrict__ pmax_part, const float* __restrict__ psum_part,
    _Float16* __restrict__ WP, _Float16* __restrict__ WQ) {
  __shared__ _Float16 T[64][72];
  __shared__ float rmx[64], rin[64], cmx[64], cin[64];
  __shared__ int sIdx[64];
  int s0 = blockIdx.x * 64, q0 = blockIdx.y * 64, b = blockIdx.z;
  int tid = threadIdx.x;
  int cntP = cntP_[b], cntQ = cntQ_[b];
  if (tid < 64) {
    int op = idxP_[b * P_ + s0 + tid];
    sIdx[tid] = op;
    float m = -INFINITY;
#pragma unroll
    for (int z = 0; z < 4; ++z) m = fmaxf(m, rpm[(b * 4 + z) * P_ + op]);
    float s = 0.f;
#pragma unroll
    for (int z = 0; z < 4; ++z)
      s += rps[(b * 4 + z) * P_ + op] * __expf(rpm[(b * 4 + z) * P_ + op] - m);
    rmx[tid] = m;
    rin[tid] = 1.0f / s;
  } else if (tid < 128) {
    int t = tid - 64;
    int qq = q0 + t;  // slot
    float m = -INFINITY;
#pragma unroll
    for (int z = 0; z < 4; ++z) m = fmaxf(m, pmax_part[(b * 4 + z) * Q_ + qq]);
    float s = 0.f;
#pragma unroll
    for (int z = 0; z < 4; ++z)
      s += psum_part[(b * 4 + z) * Q_ + qq] *
           __expf(pmax_part[(b * 4 + z) * Q_ + qq] - m);
    cmx[t] = m;
    cin[t] = 1.0f / s;
  }
  __syncthreads();
  const float* A = aff + (size_t)b * P_ * Q_;
  int rr = tid >> 4;
  int cc = (tid & 15) * 4;
  int qm[4];
#pragma unroll
  for (int j = 0; j < 4; ++j) qm[j] = (q0 + cc + j >= cntQ);
#pragma unroll
  for (int k = 0; k < 4; ++k) {
    int r = rr + k * 16;
    int orig = sIdx[r];
    int msk = (s0 + r >= cntP);
    float4 v = *(const float4*)(A + (size_t)orig * Q_ + q0 + cc);
    float vv[4] = {v.x, v.y, v.z, v.w};
    f16x4 wp;
#pragma unroll
    for (int j = 0; j < 4; ++j) {
      wp[j] = (_Float16)(__expf((qm[j] ? HUGE_NEG : vv[j]) - rmx[r]) * rin[r]);
      T[cc + j][r] =
          (_Float16)(__expf((msk ? HUGE_NEG : vv[j]) - cmx[cc + j]) * cin[cc + j]);
    }
    *(f16x4*)(WP + ((size_t)b * P_ + orig) * Q_ + q0 + cc) = wp;
  }
  __syncthreads();
  int cr = tid >> 2;
  int rc = (tid & 3) * 16;
  _Float16* D = WQ + ((size_t)b * Q_ + q0 + cr) * P_ + s0;
  *(f16x8*)(D + rc) = *(f16x8*)&T[cr][rc];
  *(f16x8*)(D + rc + 8) = *(f16x8*)&T[cr][rc + 8];
}

// ---------------------------------------------------------------------------
// GEMM core 8-wave (r8/r9-proven pipeline): 256x128 tile, 8 waves (4Mx2N),
// BK=32, 3-buffer 2-deep prefetch, counted vmcnt (6/3/0), raw barriers,
// chunk-XOR LDS swizzle, 16x16x32 MFMA. Per-lane global bases precomputed by
// caller (enables free row-gather); runtime NT (>= 2).
// ---------------------------------------------------------------------------
__device__ __forceinline__ void gemm_core(const _Float16* pA0,
                                          const _Float16* pA1,
                                          const _Float16* pB0, _Float16* As,
                                          _Float16* Bs, f32x4 (&acc)[4][4],
                                          int w, int l, int NT) {
  constexpr int ASZ = 256 * 32, BSZ = 128 * 32;
  int fr = l & 15;
  int fsw = (((l >> 4) ^ ((fr >> 1) & 3))) * 8;
  int wr = w >> 1, wc = w & 1;

  auto stage = [&](int buf, int t) {
    _Float16* la = As + buf * ASZ + (w * 32) * 32;
    _Float16* lb = Bs + buf * BSZ + (w * 16) * 32;
    dma16(pA0 + t * 32, la);
    dma16(pA1 + t * 32, la + 16 * 32);
    dma16(pB0 + t * 32, lb);
  };
  auto compute = [&](int buf) {
    const _Float16* A0 = As + buf * ASZ;
    const _Float16* B0 = Bs + buf * BSZ;
    f16x8 a[4];
#pragma unroll
    for (int m = 0; m < 4; ++m)
      a[m] = *(const f16x8*)(A0 + (wr * 64 + m * 16 + fr) * 32 + fsw);
#pragma unroll
    for (int n = 0; n < 4; ++n) {
      f16x8 bn = *(const f16x8*)(B0 + (wc * 64 + n * 16 + fr) * 32 + fsw);
#pragma unroll
      for (int m = 0; m < 4; ++m)
        acc[m][n] =
            __builtin_amdgcn_mfma_f32_16x16x32_f16(a[m], bn, acc[m][n], 0, 0, 0);
    }
  };

  stage(0, 0);
  stage(1, 1);
  int b0 = 0, b1 = 1, b2 = 2;
#pragma unroll 3
  for (int t = 0; t < NT - 2; ++t) {
    stage(b2, t + 2);
    asm volatile("s_waitcnt vmcnt(6)" ::: "memory");
    __builtin_amdgcn_s_barrier();
    __builtin_amdgcn_sched_barrier(0);
    compute(b0);
    __builtin_amdgcn_s_barrier();
    int tmp = b0; b0 = b1; b1 = b2; b2 = tmp;
  }
  asm volatile("s_waitcnt vmcnt(3)" ::: "memory");
  __builtin_amdgcn_s_barrier();
  __builtin_amdgcn_sched_barrier(0);
  compute(b0);
  __builtin_amdgcn_s_barrier();
  asm volatile("s_waitcnt vmcnt(0)" ::: "memory");
  __builtin_amdgcn_s_barrier();
  __builtin_amdgcn_sched_barrier(0);
  compute(b1);
}

#define LANE_BASES()                          \
  int rA = w * 32 + (l >> 2);                 \
  int rB = w * 16 + (l >> 2);                 \
  int sk = ((l & 3) ^ ((l >> 3) & 3)) * 8;

// bijective XCD swizzle (nwg % 8 == 0); N-tile 128, M-tile 256
#define SWZ_DECODE(GX, GY)                                          \
  int lin = blockIdx.x + (GX) * (blockIdx.y + (GY) * blockIdx.z);   \
  constexpr int NWG = (GX) * (GY) * B_;                             \
  int w8 = (lin & 7) * (NWG / 8) + (lin >> 3);                      \
  int j0 = (w8 % (GX)) * 128;                                       \
  int t_ = w8 / (GX);                                               \
  int i0 = (t_ % (GY)) * 256;                                       \
  int b = t_ / (GY);

// ---------------------------------------------------------------------------
// K1: qp[b][slot][pd] = sum_d q16[idxQ[slot]][d] * W16[pd][d]  (A row-gather)
// grid (PD/128, Q/256, B)
// ---------------------------------------------------------------------------
__global__ __launch_bounds__(512, 4) void k1_proj(
    const _Float16* __restrict__ q16, const _Float16* __restrict__ W16,
    const int* __restrict__ idxQ, _Float16* __restrict__ qp) {
  __shared__ alignas(16) _Float16 As[3 * 256 * 32];
  __shared__ alignas(16) _Float16 Bs[3 * 128 * 32];
  SWZ_DECODE(PD_ / 128, Q_ / 256)
  int tid = threadIdx.x, w = tid >> 6, l = tid & 63;
  LANE_BASES()
  const _Float16* qb = q16 + (size_t)b * Q_ * QD_;
  int o0 = idxQ[b * Q_ + i0 + rA];
  int o1 = idxQ[b * Q_ + i0 + rA + 16];
  f32x4 acc[4][4];
#pragma unroll
  for (int m = 0; m < 4; ++m)
#pragma unroll
    for (int n = 0; n < 4; ++n) acc[m][n] = (f32x4){0.f, 0.f, 0.f, 0.f};
  gemm_core(qb + (size_t)o0 * QD_ + sk, qb + (size_t)o1 * QD_ + sk,
            W16 + (size_t)(j0 + rB) * QD_ + sk, As, Bs, acc, w, l, QD_ / 32);
  int wr = w >> 1, wc = w & 1, fr = l & 15, fq = l >> 4;
  _Float16* O = qp + (size_t)b * Q_ * PD_;
#pragma unroll
  for (int m = 0; m < 4; ++m) {
    int rl = wr * 64 + m * 16 + fq * 4;
#pragma unroll
    for (int n = 0; n < 4; ++n) {
      int cl = wc * 64 + n * 16 + fr;
#pragma unroll
      for (int r = 0; r < 4; ++r)
        O[(size_t)(i0 + rl + r) * PD_ + j0 + cl] = (_Float16)acc[m][n][r];
    }
  }
}

// ---------------------------------------------------------------------------
// K2: aff[b][p][slot] = sum_d p16[p][d] * qp[slot][d]. grid (Q/128, P/256, B)
// Epilogue: fp32 aff write + softmax-stat partials:
//   col partials per q-slot (over 256 p-rows, pmask) -> pmax/psum[z=i0/256]
//   row partials per orig p (over 128 q-slots, slot>=cntQ masked) -> rpm/rps
// ---------------------------------------------------------------------------
__global__ __launch_bounds__(512, 4) void k2_aff(
    const _Float16* __restrict__ p16, const _Float16* __restrict__ qp,
    const int* __restrict__ pmask, const int* __restrict__ cntQ_,
    float* __restrict__ aff, float* __restrict__ pmax_part,
    float* __restrict__ psum_part, float* __restrict__ rpm,
    float* __restrict__ rps) {
  __shared__ alignas(16) _Float16 As[3 * 256 * 32];
  __shared__ alignas(16) _Float16 Bs[3 * 128 * 32];
  SWZ_DECODE(Q_ / 128, P_ / 256)
  int tid = threadIdx.x, w = tid >> 6, l = tid & 63;
  LANE_BASES()
  const _Float16* pb = p16 + (size_t)b * P_ * PD_;
  const _Float16* qpb = qp + (size_t)b * Q_ * PD_;
  f32x4 acc[4][4];
#pragma unroll
  for (int m = 0; m < 4; ++m)
#pragma unroll
    for (int n = 0; n < 4; ++n) acc[m][n] = (f32x4){0.f, 0.f, 0.f, 0.f};
  gemm_core(pb + (size_t)(i0 + rA) * PD_ + sk,
            pb + (size_t)(i0 + rA + 16) * PD_ + sk,
            qpb + (size_t)(j0 + rB) * PD_ + sk, As, Bs, acc, w, l, PD_ / 32);
  int wr = w >> 1, wc = w & 1, fr = l & 15, fq = l >> 4;
  float* Cb = aff + (size_t)b * P_ * Q_;
#pragma unroll
  for (int m = 0; m < 4; ++m) {
    int rl = wr * 64 + m * 16 + fq * 4;
#pragma unroll
    for (int n = 0; n < 4; ++n) {
      int cl = wc * 64 + n * 16 + fr;
#pragma unroll
      for (int r = 0; r < 4; ++r)
        Cb[(size_t)(i0 + rl + r) * Q_ + j0 + cl] = acc[m][n][r];
    }
  }
  // ---- fused softmax stat partials ----
  const int* pmb = pmask + b * P_ + i0;
  unsigned pmbits = 0;
#pragma unroll
  for (int m = 0; m < 4; ++m)
#pragma unroll
    for (int r = 0; r < 4; ++r)
      pmbits |= (pmb[wr * 64 + m * 16 + fq * 4 + r] ? 1u : 0u) << (m * 4 + r);
  int cQ = cntQ_[b];
  int qmv[4];
  {
    int cbase = j0 + wc * 64 + fr;
#pragma unroll
    for (int n = 0; n < 4; ++n) qmv[n] = (cbase + n * 16) >= cQ;
  }
  __syncthreads();
  float* scr = (float*)As;
  float* cm_ = scr;         // [4][128]
  float* cs_ = scr + 512;
  float* rm_ = scr + 1024;  // [2][256]
  float* rs_ = scr + 1536;

#pragma unroll
  for (int n = 0; n < 4; ++n) {
    float ml = -1e30f;
#pragma unroll
    for (int m = 0; m < 4; ++m)
#pragma unroll
      for (int r = 0; r < 4; ++r) {
        float v = ((pmbits >> (m * 4 + r)) & 1) ? HUGE_NEG : acc[m][n][r];
        ml = fmaxf(ml, v);
      }
    float sl = 0.f;
#pragma unroll
    for (int m = 0; m < 4; ++m)
#pragma unroll
      for (int r = 0; r < 4; ++r) {
        float v = ((pmbits >> (m * 4 + r)) & 1) ? HUGE_NEG : acc[m][n][r];
        sl += __expf(v - ml);
      }
#pragma unroll
    for (int off = 16; off <= 32; off <<= 1) {
      float om = __shfl_xor(ml, off);
      float os = __shfl_xor(sl, off);
      float nm = fmaxf(ml, om);
      sl = sl * __expf(ml - nm) + os * __expf(om - nm);
      ml = nm;
    }
    if (fq == 0) {
      int col = wc * 64 + n * 16 + fr;
      cm_[wr * 128 + col] = ml;
      cs_[wr * 128 + col] = sl;
    }
  }
#pragma unroll
  for (int m = 0; m < 4; ++m)
#pragma unroll
    for (int r = 0; r < 4; ++r) {
      float ml = -1e30f;
#pragma unroll
      for (int n = 0; n < 4; ++n) {
        float v = qmv[n] ? HUGE_NEG : acc[m][n][r];
        ml = fmaxf(ml, v);
      }
      float sl = 0.f;
#pragma unroll
      for (int n = 0; n < 4; ++n) {
        float v = qmv[n] ? HUGE_NEG : acc[m][n][r];
        sl += __expf(v - ml);
      }
#pragma unroll
      for (int off = 1; off <= 8; off <<= 1) {
        float om = __shfl_xor(ml, off);
        float os = __shfl_xor(sl, off);
        float nm = fmaxf(ml, om);
        sl = sl * __expf(ml - nm) + os * __expf(om - nm);
        ml = nm;
      }
      if (fr == 0) {
        int row = wr * 64 + m * 16 + fq * 4 + r;
        rm_[wc * 256 + row] = ml;
        rs_[wc * 256 + row] = sl;
      }
    }
  __syncthreads();
  if (tid < 128) {
    float nm = fmaxf(fmaxf(cm_[tid], cm_[128 + tid]),
                     fmaxf(cm_[256 + tid], cm_[384 + tid]));
    float ns = cs_[tid] * __expf(cm_[tid] - nm) +
               cs_[128 + tid] * __expf(cm_[128 + tid] - nm) +
               cs_[256 + tid] * __expf(cm_[256 + tid] - nm) +
               cs_[384 + tid] * __expf(cm_[384 + tid] - nm);
    int z = i0 >> 8;
    pmax_part[(b * 4 + z) * Q_ + j0 + tid] = nm;
    psum_part[(b * 4 + z) * Q_ + j0 + tid] = ns;
  } else if (tid >= 256) {
    int t = tid - 256;
    float m0 = rm_[t], m1 = rm_[256 + t];
    float s0 = rs_[t], s1 = rs_[256 + t];
    float nm = fmaxf(m0, m1);
    float ns = s0 * __expf(m0 - nm) + s1 * __expf(m1 - nm);
    int zj = j0 >> 7;
    rpm[(b * 4 + zj) * P_ + i0 + t] = nm;
    rps[(b * 4 + zj) * P_ + i0 + t] = ns;
  }
}

// ---------------------------------------------------------------------------
// K4: out2[b][idxQ[slot]][d] = sum_{p-slots<NT*32} WQ[slot][ps] * pTc[d][ps]
// Also writes candT[b][768+d][slot]. Runtime NT = ntP[b] (~halved K).
// grid (PD/128, Q/256, B)
// ---------------------------------------------------------------------------
__global__ __launch_bounds__(512, 4) void k4_attn(
    const _Float16* __restrict__ WQ, const _Float16* __restrict__ pTc,
    const int* __restrict__ idxQ, const int* __restrict__ ntP_,
    float* __restrict__ out2, _Float16* __restrict__ candT) {
  __shared__ alignas(16) _Float16 As[3 * 256 * 32];
  __shared__ alignas(16) _Float16 Bs[3 * 128 * 32];
  SWZ_DECODE(PD_ / 128, Q_ / 256)
  int tid = threadIdx.x, w = tid >> 6, l = tid & 63;
  LANE_BASES()
  const _Float16* Ab = WQ + (size_t)b * Q_ * P_;
  const _Float16* Bb = pTc + (size_t)b * PD_ * P_;
  int NT = ntP_[b];
  f32x4 acc[4][4];
#pragma unroll
  for (int m = 0; m < 4; ++m)
#pragma unroll
    for (int n = 0; n < 4; ++n) acc[m][n] = (f32x4){0.f, 0.f, 0.f, 0.f};
  gemm_core(Ab + (size_t)(i0 + rA) * P_ + sk,
            Ab + (size_t)(i0 + rA + 16) * P_ + sk,
            Bb + (size_t)(j0 + rB) * P_ + sk, As, Bs, acc, w, l, NT);
  int wr = w >> 1, wc = w & 1, fr = l & 15, fq = l >> 4;
  float* Cb = out2 + (size_t)b * Q_ * PD_;
  _Float16* Tb = candT + (size_t)b * CD_ * Q_;
  const int* iq = idxQ + b * Q_;
#pragma unroll
  for (int m = 0; m < 4; ++m) {
    int rl = wr * 64 + m * 16 + fq * 4;
    int oq[4];
#pragma unroll
    for (int r = 0; r < 4; ++r) oq[r] = iq[i0 + rl + r];
#pragma unroll
    for (int n = 0; n < 4; ++n) {
      int cl = wc * 64 + n * 16 + fr;
      f16x4 cv;
#pragma unroll
      for (int r = 0; r < 4; ++r) {
        float v = acc[m][n][r];
        Cb[(size_t)oq[r] * PD_ + j0 + cl] = v;
        cv[r] = (_Float16)v;
      }
      *(f16x4*)(Tb + (size_t)(QD_ + j0 + cl) * Q_ + i0 + rl) = cv;
    }
  }
}

// ---------------------------------------------------------------------------
// K5: out1[b][p][c] = sum_{q-slots<NT*32} WP[p][qs] * candT[c][qs]
// Runtime NT = ntQ[b] (~halved K). grid (CD/128, P/256, B)
// ---------------------------------------------------------------------------
__global__ __launch_bounds__(512, 4) void k5_attn(
    const _Float16* __restrict__ WP, const _Float16* __restrict__ candT,
    const int* __restrict__ ntQ_, float* __restrict__ out1) {
  __shared__ alignas(16) _Float16 As[3 * 256 * 32];
  __shared__ alignas(16) _Float16 Bs[3 * 128 * 32];
  SWZ_DECODE(CD_ / 128, P_ / 256)
  int tid = threadIdx.x, w = tid >> 6, l = tid & 63;
  LANE_BASES()
  const _Float16* Ab = WP + (size_t)b * P_ * Q_;
  const _Float16* Bb = candT + (size_t)b * CD_ * Q_;
  int NT = ntQ_[b];
  f32x4 acc[4][4];
#pragma unroll
  for (int m = 0; m < 4; ++m)
#pragma unroll
    for (int n = 0; n < 4; ++n) acc[m][n] = (f32x4){0.f, 0.f, 0.f, 0.f};
  gemm_core(Ab + (size_t)(i0 + rA) * Q_ + sk,
            Ab + (size_t)(i0 + rA + 16) * Q_ + sk,
            Bb + (size_t)(j0 + rB) * Q_ + sk, As, Bs, acc, w, l, NT);
  int wr = w >> 1, wc = w & 1, fr = l & 15, fq = l >> 4;
  float* Cb = out1 + (size_t)b * P_ * CD_;
#pragma unroll
  for (int m = 0; m < 4; ++m) {
    int rl = wr * 64 + m * 16 + fq * 4;
#pragma unroll
    for (int n = 0; n < 4; ++n) {
      int cl = wc * 64 + n * 16 + fr;
#pragma unroll
      for (int r = 0; r < 4; ++r)
        Cb[(size_t)(i0 + rl + r) * CD_ + j0 + cl] = acc[m][n][r];
    }
  }
}

// ---------------------------------------------------------------------------
extern "C" void kernel_launch(void* const* d_in, const int* in_sizes, int n_in,
                              void* d_out, int out_size, void* d_ws,
                              size_t ws_size, hipStream_t stream) {
  const float* p = (const float*)d_in[0];
  const float* q = (const float*)d_in[1];
  const int* pmask = (const int*)d_in[2];
  const int* qmask = (const int*)d_in[3];
  const float* W = (const float*)d_in[4];
  float* out = (float*)d_out;

  char* ws = (char*)d_ws;
  size_t off = 0;
  auto alloc = [&](size_t bytes) {
    void* r = ws + off;
    off += (bytes + 255) & ~(size_t)255;
    return r;
  };
  _Float16* q16 = (_Float16*)alloc((size_t)B_ * Q_ * QD_ * 2);
  _Float16* p16 = (_Float16*)alloc((size_t)B_ * P_ * PD_ * 2);
  _Float16* pTc = (_Float16*)alloc((size_t)B_ * PD_ * P_ * 2);
  _Float16* candT = (_Float16*)alloc((size_t)B_ * CD_ * Q_ * 2);
  _Float16* W16 = (_Float16*)alloc((size_t)PD_ * QD_ * 2);
  _Float16* qp16 = (_Float16*)alloc((size_t)B_ * Q_ * PD_ * 2);
  float* aff = (float*)alloc((size_t)B_ * P_ * Q_ * 4);
  _Float16* WP = (_Float16*)alloc((size_t)B_ * P_ * Q_ * 2);
  _Float16* WQ = (_Float16*)alloc((size_t)B_ * Q_ * P_ * 2);
  float* pmax_part = (float*)alloc((size_t)B_ * 4 * Q_ * 4);
  float* psum_part = (float*)alloc((size_t)B_ * 4 * Q_ * 4);
  float* rpm = (float*)alloc((size_t)B_ * 4 * P_ * 4);
  float* rps = (float*)alloc((size_t)B_ * 4 * P_ * 4);
  int* idxP = (int*)alloc((size_t)B_ * P_ * 4);
  int* idxQ = (int*)alloc((size_t)B_ * Q_ * 4);
  int* cntP = (int*)alloc(B_ * 4);
  int* cntQ = (int*)alloc(B_ * 4);
  int* ntP = (int*)alloc(B_ * 4);
  int* ntQ = (int*)alloc(B_ * 4);

  float* out1 = out;                          // [B,P,1536]
  float* out2 = out + (size_t)B_ * P_ * CD_;  // [B,Q,768]

  // 1. mask compaction (deterministic)
  k_index<<<B_, 256, 0, stream>>>(pmask, P_, idxP, cntP, ntP);
  k_index<<<B_, 256, 0, stream>>>(qmask, Q_, idxQ, cntQ, ntQ);
  // 2. W fp16
  k_cvt<<<PD_ * QD_ / 8 / 256, 256, 0, stream>>>(W, W16, PD_ * QD_ / 8);
  // 3. fused prep: one fp32 read each ->
  //    q: q16 (orig rows) + candT cols 0..767 (gathered transpose, slot space)
  //    p: p16 (orig rows) + pTc (gathered transpose, slot space)
  k_prep_g<<<dim3(Q_ / 64, QD_ / 64, B_), 256, 0, stream>>>(
      q, idxQ, q16, candT, Q_, QD_, (size_t)CD_ * Q_, 0);
  k_prep_g<<<dim3(P_ / 64, PD_ / 64, B_), 256, 0, stream>>>(
      p, idxP, p16, pTc, P_, PD_, (size_t)PD_ * P_, 0);
  // 4. K1 projection (A rows gathered by idxQ -> qp in slot order)
  k1_proj<<<dim3(PD_ / 128, Q_ / 256, B_), 512, 0, stream>>>(q16, W16, idxQ,
                                                             qp16);
  // 5. K2 affinity (cols = q-slots) + fused stat partials
  k2_aff<<<dim3(Q_ / 128, P_ / 256, B_), 512, 0, stream>>>(
      p16, qp16, pmask, cntQ, aff, pmax_part, psum_part, rpm, rps);
  // 6. fused weights (gathered p rows; compacted WP/WQ)
  k_w<<<dim3(P_ / 64, Q_ / 64, B_), 256, 0, stream>>>(
      aff, idxP, cntP, cntQ, rpm, rps, pmax_part, psum_part, WP, WQ);
  // 7. K4 -> out2 (rows ungathered via idxQ) + candT upper half; K ~ cntP
  k4_attn<<<dim3(PD_ / 128, Q_ / 256, B_), 512, 0, stream>>>(WQ, pTc, idxQ,
                                                             ntP, out2, candT);
  // 8. K5 -> out1; K ~ cntQ
  k5_attn<<<dim3(CD_ / 128, P_ / 256, B_), 512, 0, stream>>>(WP, candT, ntQ,
                                                             out1);
}